// Round 7
// baseline (2470.668 us; speedup 1.0000x reference)
//
#include <hip/hip_runtime.h>
#include <hip/hip_bf16.h>
#include <math.h>

// Problem dims
#define BATCH 256
#define SEQ   512
#define IN_D  512
#define HID   512
#define FOURH 2048
#define BS_ROWS (BATCH * SEQ)   // 131072

typedef __bf16 bf16x8 __attribute__((ext_vector_type(8)));
typedef float  f32x4  __attribute__((ext_vector_type(4)));
typedef unsigned uint32x4 __attribute__((ext_vector_type(4)));
typedef unsigned long long ull;

__device__ __forceinline__ float sigf(float x)  { return 1.0f / (1.0f + __expf(-x)); }
__device__ __forceinline__ float tanhf_(float x){ return 1.0f - 2.0f / (__expf(2.0f * x) + 1.0f); }

// ---------------------------------------------------------------------------
// Init: weights -> bf16, fuse biases, zero h/c exchange + flags.
// ---------------------------------------------------------------------------
__global__ __launch_bounds__(256) void init_kernel(
    const float* __restrict__ W_all_w, const float* __restrict__ W_all_b,
    const float* __restrict__ U_all_w, const float* __restrict__ U_all_b,
    const float* __restrict__ W_d_w,
    __bf16* __restrict__ Wb, __bf16* __restrict__ Ub, __bf16* __restrict__ Db,
    float* __restrict__ bias_all,
    unsigned* __restrict__ hb,            // [2][256][256] u32 pair-packed h
    unsigned* __restrict__ cb,            // [2][256][256] u32 pair-packed c
    unsigned* __restrict__ bar)           // [16 grp][2 par][32] 128B lines
{
    const int stride = gridDim.x * blockDim.x;
    const int tid0 = blockIdx.x * blockDim.x + threadIdx.x;

    const int nW = FOURH * HID;
    for (int i = tid0; i < nW; i += stride) {
        Wb[i] = (__bf16)W_all_w[i];
        Ub[i] = (__bf16)U_all_w[i];
    }
    const int nD = HID * HID;
    for (int i = tid0; i < nD; i += stride) Db[i] = (__bf16)W_d_w[i];
    for (int i = tid0; i < FOURH; i += stride) bias_all[i] = W_all_b[i] + U_all_b[i];
    for (int i = tid0; i < 2 * BATCH * 256; i += stride) { hb[i] = 0u; cb[i] = 0u; }
    for (int i = tid0; i < 16 * 2 * 32; i += stride) bar[i] = 0u;
}

// ---------------------------------------------------------------------------
// u_proj GEMM: up[B*S, 2048] = x[B*S, 512] @ U_all^T (bf16 out, no bias).
// ---------------------------------------------------------------------------
__global__ __launch_bounds__(256) void uproj_gemm(
    const float* __restrict__ x, const __bf16* __restrict__ Ub,
    __bf16* __restrict__ up)
{
    const unsigned bid = blockIdx.x;
    const unsigned lg = (bid & 7) * 2048u + (bid >> 3);   // XCD-chunked, bijective
    const int cb = lg & 15;
    const int rb = lg >> 4;

    __shared__ __bf16 As[128][64];
    __shared__ __bf16 Bs[128][64];

    const int tid = threadIdx.x;
    const int wave = tid >> 6, lane = tid & 63;
    const int wm = wave >> 1, wn = wave & 1;
    const int lrow = lane & 15, kq = lane >> 4;
    const int sw = (lrow & 7) << 3;

    f32x4 acc[4][4];
    #pragma unroll
    for (int m = 0; m < 4; ++m)
        #pragma unroll
        for (int n = 0; n < 4; ++n) acc[m][n] = (f32x4){0.f, 0.f, 0.f, 0.f};

    const int srow = tid >> 1;
    const int skc  = (tid & 1) * 32;
    const int dsw  = (srow & 7) << 3;

    for (int kk = 0; kk < 512; kk += 64) {
        {
            const float* xs = x + (size_t)(rb * 128 + srow) * 512 + kk + skc;
            #pragma unroll
            for (int j = 0; j < 4; ++j) {
                float4 va = ((const float4*)xs)[2 * j];
                float4 vb = ((const float4*)xs)[2 * j + 1];
                bf16x8 pk;
                pk[0] = (__bf16)va.x; pk[1] = (__bf16)va.y;
                pk[2] = (__bf16)va.z; pk[3] = (__bf16)va.w;
                pk[4] = (__bf16)vb.x; pk[5] = (__bf16)vb.y;
                pk[6] = (__bf16)vb.z; pk[7] = (__bf16)vb.w;
                *(bf16x8*)&As[srow][(skc + j * 8) ^ dsw] = pk;
            }
            const __bf16* bsrc = Ub + (size_t)(cb * 128 + srow) * 512 + kk + skc;
            #pragma unroll
            for (int j = 0; j < 4; ++j)
                *(uint4*)&Bs[srow][(skc + j * 8) ^ dsw] = *(const uint4*)(bsrc + j * 8);
        }
        __syncthreads();

        #pragma unroll
        for (int k2 = 0; k2 < 2; ++k2) {
            const int ke = k2 * 32 + kq * 8;
            bf16x8 af[4], bfr[4];
            #pragma unroll
            for (int m = 0; m < 4; ++m)
                af[m] = *(const bf16x8*)&As[wm * 64 + m * 16 + lrow][ke ^ sw];
            #pragma unroll
            for (int n = 0; n < 4; ++n)
                bfr[n] = *(const bf16x8*)&Bs[wn * 64 + n * 16 + lrow][ke ^ sw];
            #pragma unroll
            for (int m = 0; m < 4; ++m)
                #pragma unroll
                for (int n = 0; n < 4; ++n)
                    acc[m][n] = __builtin_amdgcn_mfma_f32_16x16x32_bf16(af[m], bfr[n], acc[m][n], 0, 0, 0);
        }
        __syncthreads();
    }

    const int colL = lane & 15, r0 = (lane >> 4) * 4;
    const size_t orow0 = (size_t)rb * 128 + wm * 64;
    const int ocol0 = cb * 128 + wn * 64;
    #pragma unroll
    for (int m = 0; m < 4; ++m)
        #pragma unroll
        for (int n = 0; n < 4; ++n)
            #pragma unroll
            for (int i = 0; i < 4; ++i)
                up[(orow0 + m * 16 + r0 + i) * 2048 + ocol0 + n * 16 + colL] = (__bf16)acc[m][n][i];
}

// ---------------------------------------------------------------------------
// Persistent scan. 256 blocks x 512 threads (8 waves), 1 block/CU.
// 16 groups x 16 blocks. Block (grp,blk): rows b0=grp*16..+15, cols k0=blk*32..+31.
// Waves 0-3: gates (4u x 2ct), K-quarter wq, A = h slice. B in 128 VGPRs.
// Waves 4-7: W_d (2ct), K-quarter wq, A = c slice; also u/ts prefetch.
// Each wave: polls only ITS 4 peer flags, gathers only ITS 4KB slice
// (coalesced 8B agent atomics, pair-packed bf16 -> direct swizzled LDS store,
// no unpack), MFMAs. Only 2 block barriers per step (S2, S3).
// ---------------------------------------------------------------------------
__global__ __launch_bounds__(512, 2) void scan_kernel(
    const __bf16* __restrict__ up,        // [B*S][2048]
    const float* __restrict__ timestamps, // [B][S]
    const __bf16* __restrict__ Wb,        // [2048][512]
    const __bf16* __restrict__ Db,        // [512][512]
    const float* __restrict__ bias_all,   // [2048]
    const float* __restrict__ Wd_b,       // [512]
    unsigned* __restrict__ hbuf,          // [2][256][256] u32 packed h pairs
    unsigned* __restrict__ cbuf,          // [2][256][256] u32 packed c pairs
    unsigned* __restrict__ bar,           // [16 grp][2 par][32]
    float* __restrict__ out)
{
    const int tid = threadIdx.x;
    const int bid = blockIdx.x;
    const int grp = bid & 15, blk = bid >> 4;
    const int b0 = grp * 16;
    const int k0 = blk * 32;
    const int wave = tid >> 6, lane = tid & 63;
    const int wq = wave & 3;              // K-quarter
    const bool is_d = (wave >= 4);
    const int lrow = lane & 15, kq = lane >> 4;
    const int swz = (lrow & 7) << 3;
    const int kbase = wq * 128 + kq * 8;

    __shared__ __bf16 Ah[16][512];        // 16 KB h tile (swizzled, per-wave slices)
    __shared__ __bf16 Ac[16][512];        // 16 KB c tile
    __shared__ float  exg[4][16][33][4];  // ~33.8 KB gate partials [u][r][kcol][wq]
    __shared__ float  exd[16][33][4];     // ~8.4 KB d partials [r][kcol][wq]
    __shared__ __bf16 Us[2][16][128];     // 8 KB u double buffer [r][g*32+kcol]
    __shared__ float  Ts[2][16];
    __shared__ float  Cm[512];            // f32 c master (r*32+kcol)
    __shared__ float  BiasW[128];         // [g*32+kcol]
    __shared__ float  BiasD[32];

    // ---- one-time: B fragments into registers ----
    bf16x8 Bg[4][2][4];   // gate waves: [unit][ct][ks]
    bf16x8 Bd[2][4];      // d waves: [ct][ks]
    if (!is_d) {
        #pragma unroll
        for (int u = 0; u < 4; ++u)
            #pragma unroll
            for (int ct = 0; ct < 2; ++ct)
                #pragma unroll
                for (int ks = 0; ks < 4; ++ks)
                    Bg[u][ct][ks] = *(const bf16x8*)(
                        Wb + (size_t)(u * 512 + k0 + ct * 16 + lrow) * 512 + kbase + ks * 32);
    } else {
        #pragma unroll
        for (int ct = 0; ct < 2; ++ct)
            #pragma unroll
            for (int ks = 0; ks < 4; ++ks)
                Bd[ct][ks] = *(const bf16x8*)(
                    Db + (size_t)(k0 + ct * 16 + lrow) * 512 + kbase + ks * 32);
    }

    // ---- preamble ----
    if (tid < 128) BiasW[tid] = bias_all[(tid >> 5) * 512 + k0 + (tid & 31)];
    else if (tid < 160) BiasD[tid - 128] = Wd_b[k0 + (tid - 128)];
    Cm[tid] = 0.f;
    if (tid < 256) {
        const int row = tid >> 4, j = tid & 15, g = j >> 2, seg = j & 3;
        uint32x4 v = __builtin_nontemporal_load(
            (const uint32x4*)(up + ((size_t)(b0 + row) * 512 + 0) * 2048
                              + g * 512 + k0 + seg * 8));
        *(uint32x4*)&Us[0][row][g * 32 + seg * 8] = v;
    }
    if (tid < 16) Ts[0][tid] = timestamps[(size_t)(b0 + tid) * 512 + 0];
    __syncthreads();

    #pragma unroll 1
    for (int t = 0; t < SEQ; ++t) {
        const int par = t & 1;

        // ---- per-wave poll: only the 4 peers owning this wave's K-slice ----
        if (t > 0) {
            const unsigned* fl = &bar[(grp * 2 + par) * 32 + wq * 4];
            for (;;) {
                unsigned f = (lane < 4)
                    ? __hip_atomic_load(&fl[lane], __ATOMIC_RELAXED, __HIP_MEMORY_SCOPE_AGENT)
                    : 0xFFFFFFFFu;
                if (__all((int)(f >= (unsigned)t))) break;
                __builtin_amdgcn_s_sleep(1);
            }
        }

        // ---- per-wave gather: own 4KB slice, coalesced 8B atomics -> LDS ----
        {
            const ull* src = (const ull*)(is_d ? cbuf : hbuf)
                           + (size_t)par * 32768 + (size_t)b0 * 128 + wq * 32 + (lane & 31);
            ull v[8];
            #pragma unroll
            for (int l = 0; l < 8; ++l)
                v[l] = __hip_atomic_load(src + (size_t)(2 * l + (lane >> 5)) * 128,
                                         __ATOMIC_RELAXED, __HIP_MEMORY_SCOPE_AGENT);
            __bf16 (* __restrict__ dst)[512] = is_d ? Ac : Ah;
            #pragma unroll
            for (int l = 0; l < 8; ++l) {
                const int row = 2 * l + (lane >> 5);
                const int e = (wq * 128 + (lane & 31) * 4) ^ ((row & 7) << 3);
                *(ull*)&dst[row][e] = v[l];
            }
        }
        asm volatile("s_waitcnt lgkmcnt(0)" ::: "memory");
        __builtin_amdgcn_sched_barrier(0);

        // ---- MFMA on own slice; d-waves also prefetch u/ts(t+1) ----
        const bool do_pf = (t + 1 < SEQ);
        if (!is_d) {
            f32x4 acc[4][2];
            #pragma unroll
            for (int u = 0; u < 4; ++u)
                #pragma unroll
                for (int ct = 0; ct < 2; ++ct) acc[u][ct] = (f32x4){0.f, 0.f, 0.f, 0.f};
            #pragma unroll
            for (int ks = 0; ks < 4; ++ks) {
                bf16x8 a = *(const bf16x8*)&Ah[lrow][(kbase + ks * 32) ^ swz];
                #pragma unroll
                for (int u = 0; u < 4; ++u)
                    #pragma unroll
                    for (int ct = 0; ct < 2; ++ct)
                        acc[u][ct] = __builtin_amdgcn_mfma_f32_16x16x32_bf16(
                            a, Bg[u][ct][ks], acc[u][ct], 0, 0, 0);
            }
            const int colL = lane & 15;
            #pragma unroll
            for (int u = 0; u < 4; ++u)
                #pragma unroll
                for (int ct = 0; ct < 2; ++ct)
                    #pragma unroll
                    for (int i = 0; i < 4; ++i)
                        exg[u][kq * 4 + i][ct * 16 + colL][wq] = acc[u][ct][i];
        } else {
            uint32x4 upf;
            float tpf = 0.f;
            const int tid2 = tid - 256;
            if (do_pf) {
                const int row = tid2 >> 4, j = tid2 & 15, g = j >> 2, seg = j & 3;
                upf = __builtin_nontemporal_load(
                    (const uint32x4*)(up + ((size_t)(b0 + row) * 512 + (t + 1)) * 2048
                                      + g * 512 + k0 + seg * 8));
                if (tid2 < 16) tpf = timestamps[(size_t)(b0 + tid2) * 512 + (t + 1)];
            }

            f32x4 accd[2];
            accd[0] = (f32x4){0.f, 0.f, 0.f, 0.f};
            accd[1] = (f32x4){0.f, 0.f, 0.f, 0.f};
            #pragma unroll
            for (int ks = 0; ks < 4; ++ks) {
                bf16x8 a = *(const bf16x8*)&Ac[lrow][(kbase + ks * 32) ^ swz];
                #pragma unroll
                for (int ct = 0; ct < 2; ++ct)
                    accd[ct] = __builtin_amdgcn_mfma_f32_16x16x32_bf16(
                        a, Bd[ct][ks], accd[ct], 0, 0, 0);
            }
            const int colL = lane & 15;
            #pragma unroll
            for (int ct = 0; ct < 2; ++ct)
                #pragma unroll
                for (int i = 0; i < 4; ++i)
                    exd[kq * 4 + i][ct * 16 + colL][wq] = accd[ct][i];

            if (do_pf) {
                const int row = tid2 >> 4, j = tid2 & 15, g = j >> 2, seg = j & 3;
                *(uint32x4*)&Us[par ^ 1][row][g * 32 + seg * 8] = upf;
                if (tid2 < 16) Ts[par ^ 1][tid2] = tpf;
            }
        }
        __syncthreads();  // S2: partials visible

        // ---- gate update: tid = r*32 + kcol; partials read as f32x4 ----
        float o_def = 0.f;
        {
            const int r = tid >> 5, kcol = tid & 31;
            f32x4 pd = *(const f32x4*)&exd[r][kcol][0];
            float g4[4];
            #pragma unroll
            for (int g = 0; g < 4; ++g) {
                f32x4 p = *(const f32x4*)&exg[g][r][kcol][0];
                g4[g] = BiasW[g * 32 + kcol] + (float)Us[par][r][g * 32 + kcol]
                      + (p[0] + p[1]) + (p[2] + p[3]);
            }
            const float dd = BiasD[kcol] + (pd[0] + pd[1]) + (pd[2] + pd[3]);

            const float c_old = Cm[tid];
            const float tt = Ts[par][r];
            const float c_s1  = tanhf_(dd);
            const float c_adj = c_old - c_s1 + c_s1 * tt;
            const float f  = sigf(g4[0]);
            const float ii = sigf(g4[1]);
            const float o  = sigf(g4[2]);
            const float c_tmp = tanhf_(g4[3]);
            const float c_new = f * c_adj + ii * c_tmp;
            const float h_new = o * tanhf_(c_new);
            Cm[tid] = c_new;

            if (t == SEQ - 1) {
                __builtin_nontemporal_store(o,
                    &out[((size_t)(b0 + r) * 512 + t) * 512 + k0 + kcol]);
                const size_t base = (size_t)BATCH * SEQ * HID;
                out[base + (size_t)(b0 + r) * 512 + k0 + kcol] = h_new;
                out[base + (size_t)BATCH * HID + (size_t)(b0 + r) * 512 + k0 + kcol] = c_new;
            } else {
                o_def = o;
                // pair-pack h/c via lane^1 shuffle, 4B agent-scope stores
                const unsigned hb16 = (unsigned)__builtin_bit_cast(unsigned short, (__bf16)h_new);
                const unsigned cb16 = (unsigned)__builtin_bit_cast(unsigned short, (__bf16)c_new);
                const unsigned hn = (unsigned)__shfl_xor((int)hb16, 1);
                const unsigned cn = (unsigned)__shfl_xor((int)cb16, 1);
                if (!(lane & 1)) {
                    const unsigned hp = hb16 | (hn << 16);
                    const unsigned cp = cb16 | (cn << 16);
                    const size_t e = (size_t)(par ^ 1) * 65536
                                   + (size_t)(b0 + r) * 256 + ((k0 + kcol) >> 1);
                    __hip_atomic_store(hbuf + e, hp, __ATOMIC_RELAXED, __HIP_MEMORY_SCOPE_AGENT);
                    __hip_atomic_store(cbuf + e, cp, __ATOMIC_RELAXED, __HIP_MEMORY_SCOPE_AGENT);
                }
            }
        }
        __syncthreads();  // S3: per-wave vmcnt drain -> h/c stores visible

        if (t < SEQ - 1) {
            if (tid == 0)
                __hip_atomic_store(&bar[(grp * 2 + ((t + 1) & 1)) * 32 + blk],
                                   (unsigned)(t + 1),
                                   __ATOMIC_RELAXED, __HIP_MEMORY_SCOPE_AGENT);
            {
                const int r = tid >> 5, kcol = tid & 31;
                __builtin_nontemporal_store(o_def,
                    &out[((size_t)(b0 + r) * 512 + t) * 512 + k0 + kcol]);
            }
        }
    }
}

// ---------------------------------------------------------------------------
extern "C" void kernel_launch(void* const* d_in, const int* in_sizes, int n_in,
                              void* d_out, int out_size, void* d_ws, size_t ws_size,
                              hipStream_t stream) {
    const float* inputs     = (const float*)d_in[0];
    const float* timestamps = (const float*)d_in[1];
    const float* W_all_w    = (const float*)d_in[2];
    const float* W_all_b    = (const float*)d_in[3];
    const float* U_all_w    = (const float*)d_in[4];
    const float* U_all_b    = (const float*)d_in[5];
    const float* W_d_w      = (const float*)d_in[6];
    const float* W_d_b      = (const float*)d_in[7];
    float* out = (float*)d_out;

    char* ws = (char*)d_ws;
    size_t off = 0;
    auto alloc = [&](size_t bytes) -> void* {
        void* p = ws + off;
        off += (bytes + 255) & ~(size_t)255;
        return p;
    };
    __bf16* Wb       = (__bf16*)alloc((size_t)FOURH * HID * 2);
    __bf16* Ub       = (__bf16*)alloc((size_t)FOURH * HID * 2);
    __bf16* Db       = (__bf16*)alloc((size_t)HID * HID * 2);
    float*  bias_all = (float*) alloc((size_t)FOURH * 4);
    unsigned* hbuf   = (unsigned*)alloc((size_t)2 * BATCH * 256 * 4);
    unsigned* cbuf   = (unsigned*)alloc((size_t)2 * BATCH * 256 * 4);
    unsigned* bar    = (unsigned*)alloc(16 * 2 * 32 * 4);
    __bf16* up       = (__bf16*)alloc((size_t)BS_ROWS * FOURH * 2);  // 512 MB

    hipLaunchKernelGGL(init_kernel, dim3(1024), dim3(256), 0, stream,
                       W_all_w, W_all_b, U_all_w, U_all_b, W_d_w,
                       Wb, Ub, Db, bias_all, hbuf, cbuf, bar);

    hipLaunchKernelGGL(uproj_gemm, dim3(16384), dim3(256), 0, stream,
                       inputs, Ub, up);

    void* sargs[] = {
        (void*)&up, (void*)&timestamps, (void*)&Wb, (void*)&Db,
        (void*)&bias_all, (void*)&W_d_b,
        (void*)&hbuf, (void*)&cbuf, (void*)&bar, (void*)&out
    };
    hipLaunchCooperativeKernel((const void*)scan_kernel, dim3(256), dim3(512),
                               sargs, 0, stream);
}